// Round 3
// baseline (568.929 us; speedup 1.0000x reference)
//
#include <hip/hip_runtime.h>

#define H 128          // hidden dim (fixed by problem)
#define CAP 64         // max edges per (rel,dst) bucket

typedef _Float16 f16x8 __attribute__((ext_vector_type(8)));
typedef _Float16 f16x2 __attribute__((ext_vector_type(2)));
typedef float    f32x4 __attribute__((ext_vector_type(4)));

// ---------------- edge bucketing: one pass, reused by both layers ----------------
__global__ __launch_bounds__(256) void hist_fill(const int* __restrict__ src,
    const int* __restrict__ dst, const int* __restrict__ et,
    int* __restrict__ cnt, int* __restrict__ elist, int E, int N)
{
    int e = blockIdx.x * 256 + threadIdx.x;
    if (e >= E) return;
    int s = src[e], d = dst[e], t = et[e];
    int b = t * N + d;
    int pos = atomicAdd(&cnt[b], 1);
    if (pos < CAP) elist[(size_t)b * CAP + pos] = s;
}

// ---------------- weight prep: transpose + fp32->fp16 ----------------
// wInT[c][k] = w_in[k][c]  (128 x K)
// w3T[m][c][k]: m=0 w_root, m=1 w_rel0, m=2 w_rel1  (each 128 x 128)
__global__ __launch_bounds__(256) void prep_w(const float* __restrict__ w_in,
    const float* __restrict__ w_root, const float* __restrict__ w_rel,
    _Float16* __restrict__ wInT, _Float16* __restrict__ w3T, int K)
{
    int idx = blockIdx.x * 256 + threadIdx.x;
    int tot1 = K * H;
    if (idx < tot1) {
        int c = idx / K, k = idx - c * K;
        wInT[idx] = (_Float16)w_in[(size_t)k * H + c];
    } else {
        int i2 = idx - tot1;
        if (i2 < 3 * H * H) {
            int m = i2 / (H * H), r2 = i2 - m * (H * H);
            int c = r2 >> 7, k = r2 & 127;
            const float* s = (m == 0) ? w_root : (w_rel + (size_t)(m - 1) * H * H);
            w3T[i2] = (_Float16)s[(size_t)k * H + c];
        }
    }
}

__device__ __forceinline__ f16x8 cvt8(float4 v0, float4 v1) {
    f16x8 t;
    t[0] = (_Float16)v0.x; t[1] = (_Float16)v0.y; t[2] = (_Float16)v0.z; t[3] = (_Float16)v0.w;
    t[4] = (_Float16)v1.x; t[5] = (_Float16)v1.y; t[6] = (_Float16)v1.z; t[7] = (_Float16)v1.w;
    return t;
}

// ---------------- big MFMA GEMM, zero-LDS: C = leakyrelu(A[M,K] @ W + b) ---------
// A fp32 row-major; WT fp16 [col][K] (L2-hot). Fragments loaded straight from
// global into registers; no barriers -> compiler software-pipelines the K loop.
__global__ __launch_bounds__(256) void gemm_big(const float* __restrict__ A,
    const _Float16* __restrict__ WT, const float* __restrict__ bias,
    float* __restrict__ C, int M, int K)
{
    const int tid = threadIdx.x;
    const int bm  = blockIdx.x * 128;
    const int w   = tid >> 6;
    const int l   = tid & 63;
    const int l15 = l & 15;
    const int q   = l >> 4;
    const int wr  = (w & 1) * 64;
    const int wc  = (w >> 1) * 64;

    const float*    ap[4];
    const _Float16* bp[4];
#pragma unroll
    for (int i = 0; i < 4; i++) {
        int row = bm + wr + i * 16 + l15;
        if (row >= M) row = M - 1;          // clamp: keeps loads in-bounds; row unused at store
        ap[i] = A + (size_t)row * K + q * 8;
    }
#pragma unroll
    for (int j = 0; j < 4; j++)
        bp[j] = WT + (size_t)(wc + j * 16 + l15) * K + q * 8;

    f32x4 acc[4][4];
    const f32x4 z4 = {0.f, 0.f, 0.f, 0.f};
#pragma unroll
    for (int i = 0; i < 4; i++)
#pragma unroll
        for (int j = 0; j < 4; j++) acc[i][j] = z4;

#pragma unroll 2
    for (int k0 = 0; k0 < K; k0 += 32) {
        f16x8 af[4], bf[4];
#pragma unroll
        for (int i = 0; i < 4; i++) {
            float4 v0 = *(const float4*)(ap[i] + k0);
            float4 v1 = *(const float4*)(ap[i] + k0 + 4);
            af[i] = cvt8(v0, v1);
        }
#pragma unroll
        for (int j = 0; j < 4; j++) bf[j] = *(const f16x8*)(bp[j] + k0);
#pragma unroll
        for (int i = 0; i < 4; i++)
#pragma unroll
            for (int j = 0; j < 4; j++)
                acc[i][j] = __builtin_amdgcn_mfma_f32_16x16x32_f16(af[i], bf[j], acc[i][j], 0, 0, 0);
    }

    // epilogue: bias + leaky, fp32 store
#pragma unroll
    for (int j = 0; j < 4; j++) {
        int col = wc + j * 16 + l15;
        float bj = bias[col];
#pragma unroll
        for (int i = 0; i < 4; i++)
#pragma unroll
            for (int rg = 0; rg < 4; rg++) {
                int row = bm + wr + i * 16 + q * 4 + rg;
                if (row < M) {
                    float v = acc[i][j][rg] + bj;
                    v = (v >= 0.f) ? v : 0.01f * v;
                    C[(size_t)row * H + col] = v;
                }
            }
    }
}

// ---------------- fused per-layer GEMM, zero-LDS ---------------------------------
// y = x@w_root + b (fp32); h_r = x@w_rel[r] (fp16, halves gather traffic).
// x-fragments loaded ONCE into registers, reused across the 3 weight matrices.
__global__ __launch_bounds__(256) void gemm3(const float* __restrict__ X,
    const _Float16* __restrict__ W3, const float* __restrict__ bias,
    float* __restrict__ Y, _Float16* __restrict__ Hh, int M)
{
    const int tid = threadIdx.x;
    const int bm  = blockIdx.x * 128;
    const int w   = tid >> 6;
    const int l   = tid & 63;
    const int l15 = l & 15;
    const int q   = l >> 4;
    const int wr  = (w & 1) * 64;
    const int wc  = (w >> 1) * 64;

    // load x-fragments once (fp32 -> fp16). OOB rows read into the next ws
    // buffer (finite values, row-independent in MFMA, never stored).
    f16x8 xf[4][4];   // [i][kk]
#pragma unroll
    for (int i = 0; i < 4; i++) {
        const float* xp = X + (size_t)(bm + wr + i * 16 + l15) * H + q * 8;
#pragma unroll
        for (int kk = 0; kk < 4; kk++) {
            float4 v0 = *(const float4*)(xp + kk * 32);
            float4 v1 = *(const float4*)(xp + kk * 32 + 4);
            xf[i][kk] = cvt8(v0, v1);
        }
    }

    const f32x4 z4 = {0.f, 0.f, 0.f, 0.f};

    for (int m = 0; m < 3; m++) {
        const _Float16* wb = W3 + (size_t)m * H * H;
        f32x4 acc[4][4];
#pragma unroll
        for (int i = 0; i < 4; i++)
#pragma unroll
            for (int j = 0; j < 4; j++) acc[i][j] = z4;

#pragma unroll
        for (int kk = 0; kk < 4; kk++) {
            f16x8 bf[4];
#pragma unroll
            for (int j = 0; j < 4; j++)
                bf[j] = *(const f16x8*)(wb + (size_t)(wc + j * 16 + l15) * H + kk * 32 + q * 8);
#pragma unroll
            for (int i = 0; i < 4; i++)
#pragma unroll
                for (int j = 0; j < 4; j++)
                    acc[i][j] = __builtin_amdgcn_mfma_f32_16x16x32_f16(xf[i][kk], bf[j], acc[i][j], 0, 0, 0);
        }

        if (m == 0) {
#pragma unroll
            for (int j = 0; j < 4; j++) {
                int col = wc + j * 16 + l15;
                float bj = bias[col];
#pragma unroll
                for (int i = 0; i < 4; i++)
#pragma unroll
                    for (int rg = 0; rg < 4; rg++) {
                        int row = bm + wr + i * 16 + q * 4 + rg;
                        if (row < M) Y[(size_t)row * H + col] = acc[i][j][rg] + bj;
                    }
            }
        } else {
            _Float16* hb = Hh + (size_t)(m - 1) * M * H;
#pragma unroll
            for (int j = 0; j < 4; j++) {
                int col = wc + j * 16 + l15;
#pragma unroll
                for (int i = 0; i < 4; i++)
#pragma unroll
                    for (int rg = 0; rg < 4; rg++) {
                        int row = bm + wr + i * 16 + q * 4 + rg;
                        if (row < M) hb[(size_t)row * H + col] = (_Float16)acc[i][j][rg];
                    }
            }
        }
    }
}

// ---------------- mean-aggregate gather: y[dst] += sum_r mean(h_r[src]) -----------
// h is fp16: 256 B per gathered row instead of 512 B.
__global__ __launch_bounds__(256) void gather_mean(float* __restrict__ y,
    const _Float16* __restrict__ h, const int* __restrict__ elist,
    const int* __restrict__ cnt, int N, int R)
{
    int wv = blockIdx.x * 4 + (threadIdx.x >> 6);
    int lane = threadIdx.x & 63;
    if (wv >= N) return;

    float2 acc = *(const float2*)&y[(size_t)wv * H + lane * 2];
    for (int r = 0; r < R; r++) {
        int b = r * N + wv;
        int deg = cnt[b];
        if (deg == 0) continue;
        int len = deg < CAP ? deg : CAP;
        const int* lst = &elist[(size_t)b * CAP];
        const _Float16* hr = h + (size_t)r * N * H;
        float sx = 0.f, sy = 0.f;
        for (int i = 0; i < len; i++) {
            int s = lst[i];
            f16x2 v = *(const f16x2*)&hr[(size_t)s * H + lane * 2];
            sx += (float)v[0]; sy += (float)v[1];
        }
        float inv = 1.0f / (float)deg;
        acc.x += sx * inv; acc.y += sy * inv;
    }
    *(float2*)&y[(size_t)wv * H + lane * 2] = acc;
}

// ---------------- final projection: out[N,OUT] = X[N,128] @ Wo[128,OUT] + bo ------
__global__ __launch_bounds__(256) void out_gemm(const float* __restrict__ X,
    const float* __restrict__ Wo, const float* __restrict__ bo,
    float* __restrict__ out, int N, int OUT)
{
    int row = blockIdx.x * 4 + (threadIdx.x >> 6);
    int lane = threadIdx.x & 63;
    if (row >= N) return;
    float a0 = X[(size_t)row * H + lane];
    float a1 = X[(size_t)row * H + 64 + lane];
    for (int c = 0; c < OUT; c++) {
        float p = a0 * Wo[lane * OUT + c] + a1 * Wo[(64 + lane) * OUT + c];
        for (int off = 32; off > 0; off >>= 1) p += __shfl_down(p, off);
        if (lane == 0) out[(size_t)row * OUT + c] = p + bo[c];
    }
}

extern "C" void kernel_launch(void* const* d_in, const int* in_sizes, int n_in,
                              void* d_out, int out_size, void* d_ws, size_t ws_size,
                              hipStream_t stream) {
    const float* feature = (const float*)d_in[0];
    const int*   ei      = (const int*)d_in[1];   // [2,E]: src then dst
    const int*   et      = (const int*)d_in[2];   // [E]
    const float* w_in    = (const float*)d_in[3];
    const float* b_in    = (const float*)d_in[4];
    const float* w_rel   = (const float*)d_in[5];
    const float* w_root  = (const float*)d_in[6];
    const float* b_conv  = (const float*)d_in[7];
    const float* w_out   = (const float*)d_in[8];
    const float* b_out   = (const float*)d_in[9];

    const int HH   = in_sizes[4];                 // 128
    const int D_IN = in_sizes[3] / HH;            // 768
    const int N    = in_sizes[0] / D_IN;          // 50000
    const int E    = in_sizes[1] / 2;             // 600000
    const int R    = in_sizes[5] / (HH * HH);     // 2
    const int OUT  = in_sizes[9];                 // 3

    // workspace layout (16B-aligned segments)
    char* base = (char*)d_ws;
    _Float16* wInT = (_Float16*)base;                              // 128*768
    _Float16* w3T  = (_Float16*)(base + (size_t)D_IN * HH * 2);    // 3*128*128
    float* x = (float*)(base + (size_t)D_IN * HH * 2 + (size_t)3 * HH * HH * 2);
    float* y = x + (size_t)N * H;
    _Float16* h = (_Float16*)(y + (size_t)N * H);                  // R*N*H fp16
    int* cnt   = (int*)(h + (size_t)R * N * H);                    // R*N
    int* elist = cnt + (size_t)R * N;                              // R*N*CAP

    hipMemsetAsync(cnt, 0, sizeof(int) * (size_t)R * N, stream);
    prep_w<<<(D_IN * HH + 3 * HH * HH + 255) / 256, 256, 0, stream>>>(
        w_in, w_root, w_rel, wInT, w3T, D_IN);
    hist_fill<<<(E + 255) / 256, 256, 0, stream>>>(ei, ei + E, et, cnt, elist, E, N);

    const int gblocks = (N + 127) / 128;
    // x = leakyrelu(feature @ w_in + b_in)
    gemm_big<<<gblocks, 256, 0, stream>>>(feature, wInT, b_in, x, N, D_IN);

    for (int layer = 0; layer < 2; layer++) {
        gemm3<<<gblocks, 256, 0, stream>>>(x, w3T, b_conv, y, h, N);
        gather_mean<<<(N + 3) / 4, 256, 0, stream>>>(y, h, elist, cnt, N, R);
        float* t = x; x = y; y = t;
    }

    out_gemm<<<(N + 3) / 4, 256, 0, stream>>>(x, w_out, b_out, (float*)d_out, N, OUT);
}